// Round 1
// baseline (201.004 us; speedup 1.0000x reference)
//
#include <hip/hip_runtime.h>
#include <float.h>

#define NB 68            // padded bins (64 + 2*2)
#define NVOX 512000      // 80*80*80
#define NBT 4760         // 2*NB + NB*NB  (sh + th + joint)
#define MAXHBLK 128      // hist blocks per batch (upper bound)
#define HTHREADS 512

// ws layout (32-bit words):
// [0..4)  ord-encoded max: [src b0, src b1, tgt b0, tgt b1]
// [4..8)  ord-encoded min
// [8 .. 8 + 2*nblk*NBT)        per-block histograms (slot = b*nblk + blk)
// [8 + 2*nblk*NBT .. +2*NBT)   final per-batch histograms

__device__ __forceinline__ unsigned f2ord(float f) {
    unsigned u = __float_as_uint(f);
    return (u & 0x80000000u) ? ~u : (u | 0x80000000u);
}
__device__ __forceinline__ float ord2f(unsigned u) {
    return (u & 0x80000000u) ? __uint_as_float(u & 0x7fffffffu)
                             : __uint_as_float(~u);
}

__global__ void k_init(unsigned* ws) {
    int i = threadIdx.x;
    if (i < 4) ws[i] = 0u;                 // max accumulators: ordered-lowest
    else if (i < 8) ws[i] = 0xFFFFFFFFu;   // min accumulators: ordered-highest
}

__global__ void k_minmax(const float* __restrict__ src,
                         const float* __restrict__ tgt, unsigned* ws) {
    int b = blockIdx.y;
    const float4* s4 = (const float4*)(src + (size_t)b * NVOX);
    const float4* t4 = (const float4*)(tgt + (size_t)b * NVOX);
    const int n4 = NVOX / 4;
    float smx = -FLT_MAX, smn = FLT_MAX, tmx = -FLT_MAX, tmn = FLT_MAX;
    for (int i = blockIdx.x * blockDim.x + threadIdx.x; i < n4;
         i += gridDim.x * blockDim.x) {
        float4 v = s4[i];
        smx = fmaxf(smx, fmaxf(fmaxf(v.x, v.y), fmaxf(v.z, v.w)));
        smn = fminf(smn, fminf(fminf(v.x, v.y), fminf(v.z, v.w)));
        float4 w = t4[i];
        tmx = fmaxf(tmx, fmaxf(fmaxf(w.x, w.y), fmaxf(w.z, w.w)));
        tmn = fminf(tmn, fminf(fminf(w.x, w.y), fminf(w.z, w.w)));
    }
#pragma unroll
    for (int m = 1; m < 64; m <<= 1) {
        smx = fmaxf(smx, __shfl_xor(smx, m));
        smn = fminf(smn, __shfl_xor(smn, m));
        tmx = fmaxf(tmx, __shfl_xor(tmx, m));
        tmn = fminf(tmn, __shfl_xor(tmn, m));
    }
    if ((threadIdx.x & 63) == 0) {
        atomicMax(&ws[0 + b], f2ord(smx));
        atomicMin(&ws[4 + b], f2ord(smn));
        atomicMax(&ws[2 + b], f2ord(tmx));
        atomicMin(&ws[6 + b], f2ord(tmn));
    }
}

__device__ __forceinline__ float bspl(float d) {
    float ad = fabsf(d);
    float a = (3.0f * ad * ad * ad - 6.0f * ad * ad + 4.0f) * (1.0f / 6.0f);
    float t = 2.0f - ad;
    float c = t * t * t * (1.0f / 6.0f);
    return ad < 1.0f ? a : (ad < 2.0f ? c : 0.0f);
}

__global__ __launch_bounds__(HTHREADS) void k_hist(
    const float* __restrict__ src, const float* __restrict__ tgt,
    float* __restrict__ wsf) {
    __shared__ float lh[NBT];
    const int b = blockIdx.y;
    const int nblk = gridDim.x;
    const unsigned* wsu = (const unsigned*)wsf;
    const float smx = ord2f(wsu[0 + b]), smn = ord2f(wsu[4 + b]);
    const float tmx = ord2f(wsu[2 + b]), tmn = ord2f(wsu[6 + b]);
    const float sbw = (smx - smn) * (1.0f / 64.0f);   // /64 is exact
    const float tbw = (tmx - tmn) * (1.0f / 64.0f);
    const float spad = smn - 2.0f * sbw;
    const float tpad = tmn - 2.0f * tbw;

    for (int i = threadIdx.x; i < NBT; i += HTHREADS) lh[i] = 0.0f;
    __syncthreads();

    const float* sp = src + (size_t)b * NVOX;
    const float* tp = tgt + (size_t)b * NVOX;
    float* sh = lh;
    float* th = lh + NB;
    float* jh = lh + 2 * NB;

    for (int i = blockIdx.x * HTHREADS + threadIdx.x; i < NVOX;
         i += nblk * HTHREADS) {
        float sv = sp[i];
        float posS = (sv - spad) / sbw;
        float fS = floorf(posS);
        fS = fminf(fmaxf(fS, 2.0f), 65.0f);
        int si = (int)fS - 1;
        float dS = posS - fS;
        float a0 = bspl(dS + 1.0f);
        float a1 = bspl(dS);
        float a2 = bspl(dS - 1.0f);
        float a3 = bspl(dS - 2.0f);

        float tv = tp[i];
        float posT = (tv - tpad) / tbw;
        float fT = floorf(posT);
        fT = fminf(fmaxf(fT, 2.0f), 65.0f);
        int ti = (int)fT - 1;
        float dT = posT - fT;
        float b0 = bspl(dT + 1.0f);
        float b1 = bspl(dT);
        float b2 = bspl(dT - 1.0f);
        float b3 = bspl(dT - 2.0f);

        atomicAdd(&sh[si + 0], a0);
        atomicAdd(&sh[si + 1], a1);
        atomicAdd(&sh[si + 2], a2);
        atomicAdd(&sh[si + 3], a3);
        atomicAdd(&th[ti + 0], b0);
        atomicAdd(&th[ti + 1], b1);
        atomicAdd(&th[ti + 2], b2);
        atomicAdd(&th[ti + 3], b3);

        float* r0 = jh + si * NB + ti;
        atomicAdd(&r0[0], a0 * b0);
        atomicAdd(&r0[1], a0 * b1);
        atomicAdd(&r0[2], a0 * b2);
        atomicAdd(&r0[3], a0 * b3);
        float* r1 = r0 + NB;
        atomicAdd(&r1[0], a1 * b0);
        atomicAdd(&r1[1], a1 * b1);
        atomicAdd(&r1[2], a1 * b2);
        atomicAdd(&r1[3], a1 * b3);
        float* r2 = r1 + NB;
        atomicAdd(&r2[0], a2 * b0);
        atomicAdd(&r2[1], a2 * b1);
        atomicAdd(&r2[2], a2 * b2);
        atomicAdd(&r2[3], a2 * b3);
        float* r3 = r2 + NB;
        atomicAdd(&r3[0], a3 * b0);
        atomicAdd(&r3[1], a3 * b1);
        atomicAdd(&r3[2], a3 * b2);
        atomicAdd(&r3[3], a3 * b3);
    }
    __syncthreads();

    float* dst = wsf + 8 + (size_t)(b * nblk + blockIdx.x) * NBT;
    for (int i = threadIdx.x; i < NBT; i += HTHREADS) dst[i] = lh[i];
}

__global__ void k_reduce(float* __restrict__ wsf, int nblk) {
    int b = blockIdx.y;
    int j = blockIdx.x * blockDim.x + threadIdx.x;
    if (j >= NBT) return;
    const float* base = wsf + 8 + (size_t)b * nblk * NBT;
    float s = 0.0f;
    for (int k = 0; k < nblk; ++k) s += base[(size_t)k * NBT + j];
    wsf[8 + (size_t)2 * nblk * NBT + (size_t)b * NBT + j] = s;
}

__device__ float bsum256(float v, float* scratch) {
#pragma unroll
    for (int m = 1; m < 64; m <<= 1) v += __shfl_xor(v, m);
    if ((threadIdx.x & 63) == 0) scratch[threadIdx.x >> 6] = v;
    __syncthreads();
    float r = scratch[0] + scratch[1] + scratch[2] + scratch[3];
    __syncthreads();
    return r;
}

__global__ __launch_bounds__(256) void k_final(const float* __restrict__ wsf,
                                               float* __restrict__ out,
                                               int nblk) {
    __shared__ float scratch[4];
    const float* fh = wsf + 8 + (size_t)2 * nblk * NBT;
    const int tid = threadIdx.x;
    for (int b = 0; b < 2; ++b) {
        const float* h = fh + (size_t)b * NBT;
        float ps = 0.0f, pt = 0.0f, pj = 0.0f;
        for (int i = tid; i < NB; i += 256) ps += h[i];
        for (int i = tid; i < NB; i += 256) pt += h[NB + i];
        for (int i = tid; i < NB * NB; i += 256) pj += h[2 * NB + i];
        float ssum = bsum256(ps, scratch);
        float tsum = bsum256(pt, scratch);
        float jsum = bsum256(pj, scratch);
        float sden = fmaxf(ssum, 1e-8f);
        float tden = fmaxf(tsum, 1e-8f);
        float jden = fmaxf(jsum, 1e-8f);
        for (int i = tid; i < NB; i += 256) out[b * NB + i] = h[i] / sden;
        for (int i = tid; i < NB; i += 256)
            out[2 * NB + b * NB + i] = h[NB + i] / tden;
        for (int i = tid; i < NB * NB; i += 256)
            out[4 * NB + b * NB * NB + i] = h[2 * NB + i] / jden;
    }
}

extern "C" void kernel_launch(void* const* d_in, const int* in_sizes, int n_in,
                              void* d_out, int out_size, void* d_ws,
                              size_t ws_size, hipStream_t stream) {
    const float* src = (const float*)d_in[0];
    const float* tgt = (const float*)d_in[1];
    float* out = (float*)d_out;
    float* wsf = (float*)d_ws;
    unsigned* wsu = (unsigned*)d_ws;

    // size hist-block count to available workspace (needs 8 + 2*nblk*NBT +
    // 2*NBT words)
    size_t avail = ws_size / 4;
    int nblk = MAXHBLK;
    if (avail < 8 + 2 * (size_t)NBT * (MAXHBLK + 1)) {
        long long room =
            ((long long)avail - 8 - 2 * (long long)NBT) / (2 * (long long)NBT);
        nblk = (int)(room < 1 ? 1 : room);
        if (nblk > MAXHBLK) nblk = MAXHBLK;
    }

    k_init<<<dim3(1), dim3(64), 0, stream>>>(wsu);
    k_minmax<<<dim3(32, 2), dim3(256), 0, stream>>>(src, tgt, wsu);
    k_hist<<<dim3(nblk, 2), dim3(HTHREADS), 0, stream>>>(src, tgt, wsf);
    k_reduce<<<dim3((NBT + 255) / 256, 2), dim3(256), 0, stream>>>(wsf, nblk);
    k_final<<<dim3(1), dim3(256), 0, stream>>>(wsf, out, nblk);
}

// Round 2
// 95.675 us; speedup vs baseline: 2.1009x; 2.1009x over previous
//
#include <hip/hip_runtime.h>
#include <float.h>

#define NB 68                 // padded bins (64 + 2*2)
#define NJ (NB * NB)          // 4624 joint bins
#define HBLK 512              // hist blocks per batch
#define HTHREADS 512
#define SCALE 2097152.0f      // 2^21 fixed-point scale
#define INV_SCALE (1.0 / 2097152.0)

// ws layout:
// words [0..4)  ord-encoded max: [src b0, src b1, tgt b0, tgt b1]
// words [4..8)  ord-encoded min
// bytes [32 .. 32 + 2*NJ*8)   u64 fixed-point joint accumulators [b][NJ]

__device__ __forceinline__ unsigned f2ord(float f) {
    unsigned u = __float_as_uint(f);
    return (u & 0x80000000u) ? ~u : (u | 0x80000000u);
}
__device__ __forceinline__ float ord2f(unsigned u) {
    return (u & 0x80000000u) ? __uint_as_float(u & 0x7fffffffu)
                             : __uint_as_float(~u);
}

__global__ void k_init(unsigned* mm, unsigned long long* J) {
    int i = blockIdx.x * 256 + threadIdx.x;
    if (i < 4) mm[i] = 0u;                  // max: ordered-lowest
    else if (i < 8) mm[i] = 0xFFFFFFFFu;    // min: ordered-highest
    for (int j = i; j < 2 * NJ; j += gridDim.x * 256) J[j] = 0ull;
}

__global__ __launch_bounds__(256) void k_minmax(const float* __restrict__ src,
                                                const float* __restrict__ tgt,
                                                unsigned* ws, int nvox) {
    int b = blockIdx.y;
    const float4* s4 = (const float4*)(src + (size_t)b * nvox);
    const float4* t4 = (const float4*)(tgt + (size_t)b * nvox);
    const int n4 = nvox / 4;
    float smx = -FLT_MAX, smn = FLT_MAX, tmx = -FLT_MAX, tmn = FLT_MAX;
    for (int i = blockIdx.x * blockDim.x + threadIdx.x; i < n4;
         i += gridDim.x * blockDim.x) {
        float4 v = s4[i];
        smx = fmaxf(smx, fmaxf(fmaxf(v.x, v.y), fmaxf(v.z, v.w)));
        smn = fminf(smn, fminf(fminf(v.x, v.y), fminf(v.z, v.w)));
        float4 w = t4[i];
        tmx = fmaxf(tmx, fmaxf(fmaxf(w.x, w.y), fmaxf(w.z, w.w)));
        tmn = fminf(tmn, fminf(fminf(w.x, w.y), fminf(w.z, w.w)));
    }
#pragma unroll
    for (int m = 1; m < 64; m <<= 1) {
        smx = fmaxf(smx, __shfl_xor(smx, m));
        smn = fminf(smn, __shfl_xor(smn, m));
        tmx = fmaxf(tmx, __shfl_xor(tmx, m));
        tmn = fminf(tmn, __shfl_xor(tmn, m));
    }
    if ((threadIdx.x & 63) == 0) {
        atomicMax(&ws[0 + b], f2ord(smx));
        atomicMin(&ws[4 + b], f2ord(smn));
        atomicMax(&ws[2 + b], f2ord(tmx));
        atomicMin(&ws[6 + b], f2ord(tmn));
    }
}

__device__ __forceinline__ float bspl(float d) {
    float ad = fabsf(d);
    float a = (3.0f * ad * ad * ad - 6.0f * ad * ad + 4.0f) * (1.0f / 6.0f);
    float t = 2.0f - ad;
    float c = t * t * t * (1.0f / 6.0f);
    return ad < 1.0f ? a : (ad < 2.0f ? c : 0.0f);
}

// Joint histogram only (1D hists are row/col sums by B-spline partition of
// unity). u32 fixed-point in LDS (native ds_add_u32, deterministic), two
// copies to halve inter-wave contention, u64 fixed-point global accumulation
// (integer -> order-independent -> deterministic).
__global__ __launch_bounds__(HTHREADS, 8) void k_hist(
    const float* __restrict__ src, const float* __restrict__ tgt,
    const unsigned* __restrict__ mm, unsigned long long* __restrict__ J,
    int nvox) {
    __shared__ unsigned lh[2 * NJ];
    const int b = blockIdx.y;
    const float smx = ord2f(mm[0 + b]), smn = ord2f(mm[4 + b]);
    const float tmx = ord2f(mm[2 + b]), tmn = ord2f(mm[6 + b]);
    const float sbw = (smx - smn) * (1.0f / 64.0f);   // /64 exact
    const float tbw = (tmx - tmn) * (1.0f / 64.0f);
    const float sinv = 1.0f / sbw, tinv = 1.0f / tbw;
    const float spad = smn - 2.0f * sbw;
    const float tpad = tmn - 2.0f * tbw;

    for (int i = threadIdx.x; i < 2 * NJ; i += HTHREADS) lh[i] = 0u;
    __syncthreads();

    unsigned* jh = lh + (threadIdx.x >> 8) * NJ;   // waves 0-3 / 4-7 split
    const float* sp = src + (size_t)b * nvox;
    const float* tp = tgt + (size_t)b * nvox;

    for (int i = blockIdx.x * HTHREADS + threadIdx.x; i < nvox;
         i += gridDim.x * HTHREADS) {
        float sv = sp[i];
        float posS = (sv - spad) * sinv;
        float fS = floorf(posS);
        fS = fminf(fmaxf(fS, 2.0f), 65.0f);
        int si = (int)fS - 1;
        float dS = posS - fS;
        float a[4];
        a[0] = bspl(dS + 1.0f);
        a[1] = bspl(dS);
        a[2] = bspl(dS - 1.0f);
        a[3] = bspl(dS - 2.0f);

        float tv = tp[i];
        float posT = (tv - tpad) * tinv;
        float fT = floorf(posT);
        fT = fminf(fmaxf(fT, 2.0f), 65.0f);
        int ti = (int)fT - 1;
        float dT = posT - fT;
        float bb[4];
        bb[0] = bspl(dT + 1.0f);
        bb[1] = bspl(dT);
        bb[2] = bspl(dT - 1.0f);
        bb[3] = bspl(dT - 2.0f);

        unsigned* base = jh + si * NB + ti;
#pragma unroll
        for (int r = 0; r < 4; ++r) {
#pragma unroll
            for (int c = 0; c < 4; ++c) {
                unsigned q = (unsigned)(a[r] * bb[c] * SCALE + 0.5f);
                atomicAdd(&base[r * NB + c], q);
            }
        }
    }
    __syncthreads();

    unsigned long long* Jb = J + (size_t)b * NJ;
    for (int i = threadIdx.x; i < NJ; i += HTHREADS) {
        unsigned s = lh[i] + lh[NJ + i];
        if (s) atomicAdd(&Jb[i], (unsigned long long)s);
    }
}

__global__ __launch_bounds__(1024) void k_final(
    const unsigned long long* __restrict__ J, float* __restrict__ out) {
    __shared__ float jf[NJ];
    __shared__ float rs[NB], cs[NB];
    __shared__ float red[16];
    const int b = blockIdx.x, tid = threadIdx.x;
    const unsigned long long* Jb = J + (size_t)b * NJ;

    float part = 0.0f;
    for (int i = tid; i < NJ; i += 1024) {
        float f = (float)((double)Jb[i] * INV_SCALE);
        jf[i] = f;
        part += f;
    }
#pragma unroll
    for (int m = 1; m < 64; m <<= 1) part += __shfl_xor(part, m);
    if ((tid & 63) == 0) red[tid >> 6] = part;
    __syncthreads();

    if (tid < NB) {                      // row sums -> source hist
        float s = 0.0f;
        for (int j = 0; j < NB; ++j) s += jf[tid * NB + j];
        rs[tid] = s;
    }
    if (tid >= 128 && tid < 128 + NB) {  // col sums -> target hist
        int c = tid - 128;
        float s = 0.0f;
        for (int r = 0; r < NB; ++r) s += jf[r * NB + c];
        cs[c] = s;
    }
    __syncthreads();

    float jsum = 0.0f;
    for (int k = 0; k < 16; ++k) jsum += red[k];
    float ssum = 0.0f, tsum = 0.0f;
    for (int k = 0; k < NB; ++k) ssum += rs[k];
    for (int k = 0; k < NB; ++k) tsum += cs[k];
    const float sden = fmaxf(ssum, 1e-8f);
    const float tden = fmaxf(tsum, 1e-8f);
    const float jden = fmaxf(jsum, 1e-8f);

    if (tid < NB) out[b * NB + tid] = rs[tid] / sden;
    if (tid >= 128 && tid < 128 + NB)
        out[2 * NB + b * NB + (tid - 128)] = cs[tid - 128] / tden;
    for (int i = tid; i < NJ; i += 1024)
        out[4 * NB + b * NJ + i] = jf[i] / jden;
}

extern "C" void kernel_launch(void* const* d_in, const int* in_sizes, int n_in,
                              void* d_out, int out_size, void* d_ws,
                              size_t ws_size, hipStream_t stream) {
    const float* src = (const float*)d_in[0];
    const float* tgt = (const float*)d_in[1];
    float* out = (float*)d_out;
    unsigned* mm = (unsigned*)d_ws;
    unsigned long long* J = (unsigned long long*)((char*)d_ws + 32);
    const int nvox = in_sizes[0] / 2;

    k_init<<<dim3(37), dim3(256), 0, stream>>>(mm, J);
    k_minmax<<<dim3(128, 2), dim3(256), 0, stream>>>(src, tgt, mm, nvox);
    k_hist<<<dim3(HBLK, 2), dim3(HTHREADS), 0, stream>>>(src, tgt, mm, J, nvox);
    k_final<<<dim3(2), dim3(1024), 0, stream>>>(J, out);
}

// Round 3
// 94.293 us; speedup vs baseline: 2.1317x; 1.0147x over previous
//
#include <hip/hip_runtime.h>
#include <float.h>

#define NB 68                 // padded bins (64 + 2*2)
#define NJ (NB * NB)          // 4624 joint bins
#define HBLK 512              // hist blocks per batch
#define HTHREADS 512
#define SCALE 2097152.0f      // 2^21 fixed-point scale
#define INV_SCALE (1.0 / 2097152.0)

// ws layout:
// words [0..4)  ord-encoded max: [src b0, src b1, tgt b0, tgt b1]
// words [4..8)  ord-encoded min
// bytes [32 .. 32 + 2*NJ*8)   u64 fixed-point joint accumulators [b][NJ]

__device__ __forceinline__ unsigned f2ord(float f) {
    unsigned u = __float_as_uint(f);
    return (u & 0x80000000u) ? ~u : (u | 0x80000000u);
}
__device__ __forceinline__ float ord2f(unsigned u) {
    return (u & 0x80000000u) ? __uint_as_float(u & 0x7fffffffu)
                             : __uint_as_float(~u);
}

__global__ void k_init(unsigned* mm, unsigned long long* J) {
    int i = blockIdx.x * 256 + threadIdx.x;
    if (i < 4) mm[i] = 0u;                  // max: ordered-lowest
    else if (i < 8) mm[i] = 0xFFFFFFFFu;    // min: ordered-highest
    for (int j = i; j < 2 * NJ; j += gridDim.x * 256) J[j] = 0ull;
}

// One float4 per array per thread: all loads in flight at once (latency fix).
// Per-block LDS reduction -> 1 atomic set per block (tames same-address
// atomic serialization).
__global__ __launch_bounds__(256) void k_minmax(const float* __restrict__ src,
                                                const float* __restrict__ tgt,
                                                unsigned* ws, int n4) {
    __shared__ float red[4][4];   // [wave][smx,smn,tmx,tmn]
    const int b = blockIdx.y;
    const int i = blockIdx.x * 256 + threadIdx.x;
    float smx = -FLT_MAX, smn = FLT_MAX, tmx = -FLT_MAX, tmn = FLT_MAX;
    if (i < n4) {
        const float4* s4 = (const float4*)src + (size_t)b * n4;
        const float4* t4 = (const float4*)tgt + (size_t)b * n4;
        float4 v = s4[i];
        float4 w = t4[i];
        smx = fmaxf(fmaxf(v.x, v.y), fmaxf(v.z, v.w));
        smn = fminf(fminf(v.x, v.y), fminf(v.z, v.w));
        tmx = fmaxf(fmaxf(w.x, w.y), fmaxf(w.z, w.w));
        tmn = fminf(fminf(w.x, w.y), fminf(w.z, w.w));
    }
#pragma unroll
    for (int m = 1; m < 64; m <<= 1) {
        smx = fmaxf(smx, __shfl_xor(smx, m));
        smn = fminf(smn, __shfl_xor(smn, m));
        tmx = fmaxf(tmx, __shfl_xor(tmx, m));
        tmn = fminf(tmn, __shfl_xor(tmn, m));
    }
    const int wave = threadIdx.x >> 6;
    if ((threadIdx.x & 63) == 0) {
        red[wave][0] = smx;
        red[wave][1] = smn;
        red[wave][2] = tmx;
        red[wave][3] = tmn;
    }
    __syncthreads();
    if (threadIdx.x == 0) {
        smx = fmaxf(fmaxf(red[0][0], red[1][0]), fmaxf(red[2][0], red[3][0]));
        smn = fminf(fminf(red[0][1], red[1][1]), fminf(red[2][1], red[3][1]));
        tmx = fmaxf(fmaxf(red[0][2], red[1][2]), fmaxf(red[2][2], red[3][2]));
        tmn = fminf(fminf(red[0][3], red[1][3]), fminf(red[2][3], red[3][3]));
        atomicMax(&ws[0 + b], f2ord(smx));
        atomicMin(&ws[4 + b], f2ord(smn));
        atomicMax(&ws[2 + b], f2ord(tmx));
        atomicMin(&ws[6 + b], f2ord(tmn));
    }
}

__device__ __forceinline__ float bspl(float d) {
    float ad = fabsf(d);
    float a = (3.0f * ad * ad * ad - 6.0f * ad * ad + 4.0f) * (1.0f / 6.0f);
    float t = 2.0f - ad;
    float c = t * t * t * (1.0f / 6.0f);
    return ad < 1.0f ? a : (ad < 2.0f ? c : 0.0f);
}

// Joint histogram only (1D hists are row/col sums by B-spline partition of
// unity). u32 fixed-point in LDS (native ds_add_u32, deterministic), two
// copies to halve inter-wave contention, u64 fixed-point global accumulation
// (integer -> order-independent -> deterministic).
__global__ __launch_bounds__(HTHREADS, 8) void k_hist(
    const float* __restrict__ src, const float* __restrict__ tgt,
    const unsigned* __restrict__ mm, unsigned long long* __restrict__ J,
    int nvox) {
    __shared__ unsigned lh[2 * NJ];
    const int b = blockIdx.y;
    const float smx = ord2f(mm[0 + b]), smn = ord2f(mm[4 + b]);
    const float tmx = ord2f(mm[2 + b]), tmn = ord2f(mm[6 + b]);
    const float sbw = (smx - smn) * (1.0f / 64.0f);   // /64 exact
    const float tbw = (tmx - tmn) * (1.0f / 64.0f);
    const float sinv = 1.0f / sbw, tinv = 1.0f / tbw;
    const float spad = smn - 2.0f * sbw;
    const float tpad = tmn - 2.0f * tbw;

    for (int i = threadIdx.x; i < 2 * NJ; i += HTHREADS) lh[i] = 0u;
    __syncthreads();

    unsigned* jh = lh + (threadIdx.x >> 8) * NJ;   // waves 0-3 / 4-7 split
    const float* sp = src + (size_t)b * nvox;
    const float* tp = tgt + (size_t)b * nvox;

    for (int i = blockIdx.x * HTHREADS + threadIdx.x; i < nvox;
         i += gridDim.x * HTHREADS) {
        float sv = sp[i];
        float posS = (sv - spad) * sinv;
        float fS = floorf(posS);
        fS = fminf(fmaxf(fS, 2.0f), 65.0f);
        int si = (int)fS - 1;
        float dS = posS - fS;
        float a[4];
        a[0] = bspl(dS + 1.0f);
        a[1] = bspl(dS);
        a[2] = bspl(dS - 1.0f);
        a[3] = bspl(dS - 2.0f);

        float tv = tp[i];
        float posT = (tv - tpad) * tinv;
        float fT = floorf(posT);
        fT = fminf(fmaxf(fT, 2.0f), 65.0f);
        int ti = (int)fT - 1;
        float dT = posT - fT;
        float bb[4];
        bb[0] = bspl(dT + 1.0f);
        bb[1] = bspl(dT);
        bb[2] = bspl(dT - 1.0f);
        bb[3] = bspl(dT - 2.0f);

        unsigned* base = jh + si * NB + ti;
#pragma unroll
        for (int r = 0; r < 4; ++r) {
#pragma unroll
            for (int c = 0; c < 4; ++c) {
                unsigned q = (unsigned)(a[r] * bb[c] * SCALE + 0.5f);
                atomicAdd(&base[r * NB + c], q);
            }
        }
    }
    __syncthreads();

    unsigned long long* Jb = J + (size_t)b * NJ;
    for (int i = threadIdx.x; i < NJ; i += HTHREADS) {
        unsigned s = lh[i] + lh[NJ + i];
        if (s) atomicAdd(&Jb[i], (unsigned long long)s);
    }
}

__global__ __launch_bounds__(1024) void k_final(
    const unsigned long long* __restrict__ J, float* __restrict__ out) {
    __shared__ float jf[NJ];
    __shared__ float rs[NB], cs[NB];
    __shared__ float red[16];
    const int b = blockIdx.x, tid = threadIdx.x;
    const unsigned long long* Jb = J + (size_t)b * NJ;

    float part = 0.0f;
    for (int i = tid; i < NJ; i += 1024) {
        float f = (float)((double)Jb[i] * INV_SCALE);
        jf[i] = f;
        part += f;
    }
#pragma unroll
    for (int m = 1; m < 64; m <<= 1) part += __shfl_xor(part, m);
    if ((tid & 63) == 0) red[tid >> 6] = part;
    __syncthreads();

    if (tid < NB) {                      // row sums -> source hist
        float s = 0.0f;
        for (int j = 0; j < NB; ++j) s += jf[tid * NB + j];
        rs[tid] = s;
    }
    if (tid >= 128 && tid < 128 + NB) {  // col sums -> target hist
        int c = tid - 128;
        float s = 0.0f;
        for (int r = 0; r < NB; ++r) s += jf[r * NB + c];
        cs[c] = s;
    }
    __syncthreads();

    float jsum = 0.0f;
    for (int k = 0; k < 16; ++k) jsum += red[k];
    float ssum = 0.0f, tsum = 0.0f;
    for (int k = 0; k < NB; ++k) ssum += rs[k];
    for (int k = 0; k < NB; ++k) tsum += cs[k];
    const float sden = fmaxf(ssum, 1e-8f);
    const float tden = fmaxf(tsum, 1e-8f);
    const float jden = fmaxf(jsum, 1e-8f);

    if (tid < NB) out[b * NB + tid] = rs[tid] / sden;
    if (tid >= 128 && tid < 128 + NB)
        out[2 * NB + b * NB + (tid - 128)] = cs[tid - 128] / tden;
    for (int i = tid; i < NJ; i += 1024)
        out[4 * NB + b * NJ + i] = jf[i] / jden;
}

extern "C" void kernel_launch(void* const* d_in, const int* in_sizes, int n_in,
                              void* d_out, int out_size, void* d_ws,
                              size_t ws_size, hipStream_t stream) {
    const float* src = (const float*)d_in[0];
    const float* tgt = (const float*)d_in[1];
    float* out = (float*)d_out;
    unsigned* mm = (unsigned*)d_ws;
    unsigned long long* J = (unsigned long long*)((char*)d_ws + 32);
    const int nvox = in_sizes[0] / 2;
    const int n4 = nvox / 4;

    k_init<<<dim3(37), dim3(256), 0, stream>>>(mm, J);
    k_minmax<<<dim3((n4 + 255) / 256, 2), dim3(256), 0, stream>>>(src, tgt, mm,
                                                                  n4);
    k_hist<<<dim3(HBLK, 2), dim3(HTHREADS), 0, stream>>>(src, tgt, mm, J, nvox);
    k_final<<<dim3(2), dim3(1024), 0, stream>>>(J, out);
}

// Round 5
// 32.366 us; speedup vs baseline: 6.2104x; 2.9133x over previous
//
#include <hip/hip_runtime.h>
#include <float.h>

#define NB 68                 // padded bins (64 + 2*2)
#define NJ (NB * NB)          // 4624 joint bins
#define HBLK 128              // hist blocks per batch
#define HTHREADS 512
#define NCOPY 2               // LDS histogram copies per block
#define SCALE 2097152.0f      // 2^21 fixed-point scale
#define INV_SCALE (1.0 / 2097152.0)

// ws layout (bytes):
// [0   .. 32)   mm floats: [0..1]=smx(b), [2..3]=tmx(b), [4..5]=smn(b), [6..7]=tmn(b)
// [64  .. 64+2*128*16)  P: per-block minmax partials, float4 {smx,smn,tmx,tmn}
// [4160 .. 4160+2*NJ*8) J: u64 fixed-point joint accumulators [b][NJ]

__global__ void k_init(unsigned long long* J) {
    int i = blockIdx.x * 1024 + threadIdx.x;
    if (i < 2 * NJ) J[i] = 0ull;
}

// Stage 1: one float4 of src and tgt per thread (all loads in flight),
// block-reduce, ONE plain float4 store per block. No atomics.
__global__ __launch_bounds__(1024) void k_mm_part(const float* __restrict__ src,
                                                  const float* __restrict__ tgt,
                                                  float4* __restrict__ P,
                                                  int n4) {
    __shared__ float red[16][4];
    const int b = blockIdx.y;
    const int i = blockIdx.x * 1024 + threadIdx.x;
    float smx = -FLT_MAX, smn = FLT_MAX, tmx = -FLT_MAX, tmn = FLT_MAX;
    if (i < n4) {
        const float4* s4 = (const float4*)src + (size_t)b * n4;
        const float4* t4 = (const float4*)tgt + (size_t)b * n4;
        float4 v = s4[i];
        float4 w = t4[i];
        smx = fmaxf(fmaxf(v.x, v.y), fmaxf(v.z, v.w));
        smn = fminf(fminf(v.x, v.y), fminf(v.z, v.w));
        tmx = fmaxf(fmaxf(w.x, w.y), fmaxf(w.z, w.w));
        tmn = fminf(fminf(w.x, w.y), fminf(w.z, w.w));
    }
#pragma unroll
    for (int m = 1; m < 64; m <<= 1) {
        smx = fmaxf(smx, __shfl_xor(smx, m));
        smn = fminf(smn, __shfl_xor(smn, m));
        tmx = fmaxf(tmx, __shfl_xor(tmx, m));
        tmn = fminf(tmn, __shfl_xor(tmn, m));
    }
    const int wave = threadIdx.x >> 6;
    if ((threadIdx.x & 63) == 0) {
        red[wave][0] = smx;
        red[wave][1] = smn;
        red[wave][2] = tmx;
        red[wave][3] = tmn;
    }
    __syncthreads();
    if (threadIdx.x == 0) {
#pragma unroll
        for (int k = 1; k < 16; ++k) {
            smx = fmaxf(smx, red[k][0]);
            smn = fminf(smn, red[k][1]);
            tmx = fmaxf(tmx, red[k][2]);
            tmn = fminf(tmn, red[k][3]);
        }
        P[b * 128 + blockIdx.x] = make_float4(smx, smn, tmx, tmn);
    }
}

// Stage 2: reduce the 125 per-block partials per batch, plain stores to mm.
__global__ __launch_bounds__(128) void k_mm_final(const float4* __restrict__ P,
                                                  float* __restrict__ mm,
                                                  int nblk) {
    __shared__ float r2[2][4];
    const int b = blockIdx.x;
    const int k = threadIdx.x;
    float smx = -FLT_MAX, smn = FLT_MAX, tmx = -FLT_MAX, tmn = FLT_MAX;
    if (k < nblk) {
        float4 v = P[b * 128 + k];
        smx = v.x; smn = v.y; tmx = v.z; tmn = v.w;
    }
#pragma unroll
    for (int m = 1; m < 64; m <<= 1) {
        smx = fmaxf(smx, __shfl_xor(smx, m));
        smn = fminf(smn, __shfl_xor(smn, m));
        tmx = fmaxf(tmx, __shfl_xor(tmx, m));
        tmn = fminf(tmn, __shfl_xor(tmn, m));
    }
    if ((k & 63) == 0) {
        r2[k >> 6][0] = smx;
        r2[k >> 6][1] = smn;
        r2[k >> 6][2] = tmx;
        r2[k >> 6][3] = tmn;
    }
    __syncthreads();
    if (k == 0) {
        mm[0 + b] = fmaxf(r2[0][0], r2[1][0]);   // smx
        mm[4 + b] = fminf(r2[0][1], r2[1][1]);   // smn
        mm[2 + b] = fmaxf(r2[0][2], r2[1][2]);   // tmx
        mm[6 + b] = fminf(r2[0][3], r2[1][3]);   // tmn
    }
}

__device__ __forceinline__ float bspl(float d) {
    float ad = fabsf(d);
    float a = (3.0f * ad * ad * ad - 6.0f * ad * ad + 4.0f) * (1.0f / 6.0f);
    float t = 2.0f - ad;
    float c = t * t * t * (1.0f / 6.0f);
    return ad < 1.0f ? a : (ad < 2.0f ? c : 0.0f);
}

__device__ __forceinline__ void vox1(float sv, float tv, unsigned* jh,
                                     float spad, float sinv, float tpad,
                                     float tinv) {
    float posS = (sv - spad) * sinv;
    float fS = floorf(posS);
    fS = fminf(fmaxf(fS, 2.0f), 65.0f);
    int si = (int)fS - 1;
    float dS = posS - fS;
    float a0 = bspl(dS + 1.0f), a1 = bspl(dS), a2 = bspl(dS - 1.0f),
          a3 = bspl(dS - 2.0f);

    float posT = (tv - tpad) * tinv;
    float fT = floorf(posT);
    fT = fminf(fmaxf(fT, 2.0f), 65.0f);
    int ti = (int)fT - 1;
    float dT = posT - fT;
    float b0 = bspl(dT + 1.0f), b1 = bspl(dT), b2 = bspl(dT - 1.0f),
          b3 = bspl(dT - 2.0f);

    unsigned* base = jh + si * NB + ti;
    float a[4] = {a0, a1, a2, a3};
    float bb[4] = {b0, b1, b2, b3};
#pragma unroll
    for (int r = 0; r < 4; ++r) {
#pragma unroll
        for (int c = 0; c < 4; ++c) {
            unsigned q = (unsigned)(a[r] * bb[c] * SCALE + 0.5f);
            atomicAdd(&base[r * NB + c], q);
        }
    }
}

// Joint histogram only (1D hists are row/col sums by B-spline partition of
// unity). u32 fixed-point LDS (native ds_add), float4 voxel loads with both
// iterations' loads issued up front, u64 global atomic flush (256 blocks
// total -> ~1.2M atomics over 578 lines).
__global__ __launch_bounds__(HTHREADS) void k_hist(
    const float* __restrict__ src, const float* __restrict__ tgt,
    const float* __restrict__ mm, unsigned long long* __restrict__ J, int n4) {
    __shared__ unsigned lh[NCOPY * NJ];
    const int b = blockIdx.y;
    const float smx = mm[0 + b], tmx = mm[2 + b];
    const float smn = mm[4 + b], tmn = mm[6 + b];
    const float sbw = (smx - smn) * (1.0f / 64.0f);
    const float tbw = (tmx - tmn) * (1.0f / 64.0f);
    const float sinv = 1.0f / sbw, tinv = 1.0f / tbw;
    const float spad = smn - 2.0f * sbw;
    const float tpad = tmn - 2.0f * tbw;

    for (int i = threadIdx.x; i < NCOPY * NJ; i += HTHREADS) lh[i] = 0u;
    __syncthreads();

    unsigned* jh = lh + (threadIdx.x >> 8) * NJ;   // waves 0-3 / 4-7
    const float4* s4 = (const float4*)src + (size_t)b * n4;
    const float4* t4 = (const float4*)tgt + (size_t)b * n4;
    const int STRIDE = HBLK * HTHREADS;            // 65536 float4s
    const int i0 = blockIdx.x * HTHREADS + threadIdx.x;
    const int i1 = i0 + STRIDE;

    float4 sA = s4[i0], tA = t4[i0];
    bool has2 = i1 < n4;
    float4 sB, tB;
    if (has2) { sB = s4[i1]; tB = t4[i1]; }

    vox1(sA.x, tA.x, jh, spad, sinv, tpad, tinv);
    vox1(sA.y, tA.y, jh, spad, sinv, tpad, tinv);
    vox1(sA.z, tA.z, jh, spad, sinv, tpad, tinv);
    vox1(sA.w, tA.w, jh, spad, sinv, tpad, tinv);
    if (has2) {
        vox1(sB.x, tB.x, jh, spad, sinv, tpad, tinv);
        vox1(sB.y, tB.y, jh, spad, sinv, tpad, tinv);
        vox1(sB.z, tB.z, jh, spad, sinv, tpad, tinv);
        vox1(sB.w, tB.w, jh, spad, sinv, tpad, tinv);
    }
    // generic tail (not taken for the 80^3 shape)
    for (int i = i0 + 2 * STRIDE; i < n4; i += STRIDE) {
        float4 s = s4[i], t = t4[i];
        vox1(s.x, t.x, jh, spad, sinv, tpad, tinv);
        vox1(s.y, t.y, jh, spad, sinv, tpad, tinv);
        vox1(s.z, t.z, jh, spad, sinv, tpad, tinv);
        vox1(s.w, t.w, jh, spad, sinv, tpad, tinv);
    }
    __syncthreads();

    unsigned long long* Jb = J + (size_t)b * NJ;
    for (int i = threadIdx.x; i < NJ; i += HTHREADS) {
        unsigned long long s = (unsigned long long)lh[i] + lh[NJ + i];
        if (s) atomicAdd(&Jb[i], s);
    }
}

__global__ __launch_bounds__(1024) void k_final(
    const unsigned long long* __restrict__ J, float* __restrict__ out) {
    __shared__ float jf[NJ];
    __shared__ float rs[NB], cs[NB];
    __shared__ float red[16];
    const int b = blockIdx.x, tid = threadIdx.x;
    const unsigned long long* Jb = J + (size_t)b * NJ;

    float part = 0.0f;
    for (int i = tid; i < NJ; i += 1024) {
        float f = (float)((double)Jb[i] * INV_SCALE);
        jf[i] = f;
        part += f;
    }
#pragma unroll
    for (int m = 1; m < 64; m <<= 1) part += __shfl_xor(part, m);
    if ((tid & 63) == 0) red[tid >> 6] = part;
    __syncthreads();

    if (tid < NB) {                      // row sums -> source hist
        float s = 0.0f;
        for (int j = 0; j < NB; ++j) s += jf[tid * NB + j];
        rs[tid] = s;
    }
    if (tid >= 128 && tid < 128 + NB) {  // col sums -> target hist
        int c = tid - 128;
        float s = 0.0f;
        for (int r = 0; r < NB; ++r) s += jf[r * NB + c];
        cs[c] = s;
    }
    __syncthreads();

    float jsum = 0.0f;
    for (int k = 0; k < 16; ++k) jsum += red[k];
    float ssum = 0.0f, tsum = 0.0f;
    for (int k = 0; k < NB; ++k) ssum += rs[k];
    for (int k = 0; k < NB; ++k) tsum += cs[k];
    const float sden = fmaxf(ssum, 1e-8f);
    const float tden = fmaxf(tsum, 1e-8f);
    const float jden = fmaxf(jsum, 1e-8f);

    if (tid < NB) out[b * NB + tid] = rs[tid] / sden;
    if (tid >= 128 && tid < 128 + NB)
        out[2 * NB + b * NB + (tid - 128)] = cs[tid - 128] / tden;
    for (int i = tid; i < NJ; i += 1024)
        out[4 * NB + b * NJ + i] = jf[i] / jden;
}

extern "C" void kernel_launch(void* const* d_in, const int* in_sizes, int n_in,
                              void* d_out, int out_size, void* d_ws,
                              size_t ws_size, hipStream_t stream) {
    const float* src = (const float*)d_in[0];
    const float* tgt = (const float*)d_in[1];
    float* out = (float*)d_out;
    float* mm = (float*)d_ws;
    float4* P = (float4*)((char*)d_ws + 64);
    unsigned long long* J = (unsigned long long*)((char*)d_ws + 4160);
    const int nvox = in_sizes[0] / 2;
    const int n4 = nvox / 4;                      // 128000
    const int mmblk = (n4 + 1023) / 1024;         // 125

    k_init<<<dim3((2 * NJ + 1023) / 1024), dim3(1024), 0, stream>>>(J);
    k_mm_part<<<dim3(mmblk, 2), dim3(1024), 0, stream>>>(src, tgt, P, n4);
    k_mm_final<<<dim3(2), dim3(128), 0, stream>>>(P, mm, mmblk);
    k_hist<<<dim3(HBLK, 2), dim3(HTHREADS), 0, stream>>>(src, tgt, mm, J, n4);
    k_final<<<dim3(2), dim3(1024), 0, stream>>>(J, out);
}